// Round 5
// baseline (1824.825 us; speedup 1.0000x reference)
//
#include <hip/hip_runtime.h>

#define N_PIX   (32 * 64 * 64)          // 131072 pixel rows
#define E_DIM   64
#define N_E     1024
#define Z_ELEMS (N_PIX * E_DIM)         // 8388608

#define LOSS_OFF 0
#define ZQ_OFF   1
#define PERP_OFF (1 + Z_ELEMS)                          // 8388609
#define ENC_OFF  ((size_t)(2 + Z_ELEMS))                // 8388610
#define IDX_OFF  (ENC_OFF + (size_t)N_PIX * N_E)        // 142606338

typedef float f32x2 __attribute__((ext_vector_type(2)));
typedef float f32x4 __attribute__((ext_vector_type(4)));

// DPP cross-lane adds within each 4-lane group (VALU pipe, no LDS traffic).
__device__ __forceinline__ float dpp_add_xor1(float v) {
    int i = __builtin_bit_cast(int, v);
    i = __builtin_amdgcn_mov_dpp(i, 0xB1, 0xF, 0xF, true);  // quad_perm(1,0,3,2)
    return v + __builtin_bit_cast(float, i);
}
__device__ __forceinline__ float dpp_add_xor2(float v) {
    int i = __builtin_bit_cast(int, v);
    i = __builtin_amdgcn_mov_dpp(i, 0x4E, 0xF, 0xF, true);  // quad_perm(2,3,0,1)
    return v + __builtin_bit_cast(float, i);
}

// ---- precompute ||e||^2 per codebook row ----
__global__ void vq_prep(const float* __restrict__ emb, float* __restrict__ ee) {
    int e = blockIdx.x * blockDim.x + threadIdx.x;
    if (e < N_E) {
        const float* r = emb + e * E_DIM;
        float s0 = 0.f, s1 = 0.f, s2 = 0.f, s3 = 0.f;
        #pragma unroll
        for (int c = 0; c < E_DIM; c += 4) {
            s0 = fmaf(r[c],     r[c],     s0);
            s1 = fmaf(r[c + 1], r[c + 1], s1);
            s2 = fmaf(r[c + 2], r[c + 2], s2);
            s3 = fmaf(r[c + 3], r[c + 3], s3);
        }
        ee[e] = (s0 + s1) + (s2 + s3);
    }
}

// ---- main: 4 lanes per pixel (16 channels each) ----
// grid = 2048 blocks x 256 threads = 8192 waves (32/CU) -> real latency hiding.
// Per-thread live set ~16 z floats -> low VGPR pressure by construction.
// NOTE: d MUST be computed as zz + ee[e] - 2*dot (with the dominant zz term):
// the fp32 reference's d is quantized at ULP(zz) and its argmin resolves the
// resulting ties by first-index; dropping zz un-quantizes our d and flips
// those ties (R4 failure, indices absmax 1007).
__global__ __launch_bounds__(256, 4) void vq_main(
    const float* __restrict__ z, const float* __restrict__ emb,
    const float* __restrict__ ee, float* __restrict__ out,
    unsigned* __restrict__ counts, double* __restrict__ loss_acc)
{
    const int tid = threadIdx.x;
    const int s   = tid & 3;                  // channel quarter 0..3
    const int pl  = tid >> 2;                 // local pixel 0..63
    const int p   = blockIdx.x * 64 + pl;     // global pixel = b*4096 + hw
    const int b   = p >> 12;
    const int hw  = p & 4095;
    const int c0  = s << 4;                   // first channel of my quarter

    // ---- load my 16 channels of z (strided 4096 floats; coalesced per instr) ----
    const float* zp = z + ((size_t)b * E_DIM + c0) * 4096 + hw;
    f32x4 zv[4];
    #pragma unroll
    for (int j = 0; j < 4; ++j) {
        zv[j][0] = zp[(size_t)(4 * j    ) * 4096];
        zv[j][1] = zp[(size_t)(4 * j + 1) * 4096];
        zv[j][2] = zp[(size_t)(4 * j + 2) * 4096];
        zv[j][3] = zp[(size_t)(4 * j + 3) * 4096];
    }

    // ---- zz = ||z_row||^2 (same tree shape as dot below) ----
    f32x4 zacc = {0.f, 0.f, 0.f, 0.f};
    #pragma unroll
    for (int j = 0; j < 4; ++j)
        zacc = __builtin_elementwise_fma(zv[j], zv[j], zacc);
    f32x2 zt = __builtin_shufflevector(zacc, zacc, 0, 1)
             + __builtin_shufflevector(zacc, zacc, 2, 3);
    float zz = zt.x + zt.y;
    zz = dpp_add_xor1(zz);
    zz = dpp_add_xor2(zz);      // all 4 lanes hold full 64-ch zz

    // ---- argmin over codes ----
    float dmin = 3.4e38f;
    int   best = 0;
    #pragma unroll 2
    for (int e = 0; e < N_E; ++e) {
        const f32x4* er = (const f32x4*)(emb + (e << 6) + c0);
        f32x4 acc = {0.f, 0.f, 0.f, 0.f};
        #pragma unroll
        for (int j = 0; j < 4; ++j)
            acc = __builtin_elementwise_fma(zv[j], er[j], acc);   // v_pk_fma_f32 x2
        f32x2 t2 = __builtin_shufflevector(acc, acc, 0, 1)
                 + __builtin_shufflevector(acc, acc, 2, 3);
        float dot = t2.x + t2.y;          // my 16-ch partial
        dot = dpp_add_xor1(dot);          // + partner lane
        dot = dpp_add_xor2(dot);          // all 4 lanes now hold full 64-ch dot
        const float d = zz + ee[e] - 2.0f * dot;   // reference-matching rounding
        if (d < dmin) { dmin = d; best = e; }      // strict < = first-index tie-break
    }

    // ---- index + histogram (group leader only; best is uniform in group) ----
    if (s == 0) {
        out[IDX_OFF + p] = (float)best;
        atomicAdd(&counts[best], 1u);
    }

    // ---- z_q (NCHW, NT stores) + loss partial over my 16 channels ----
    const f32x4* eb = (const f32x4*)(emb + (best << 6) + c0);
    float* zqp = out + ZQ_OFF + ((size_t)b * E_DIM + c0) * 4096 + hw;
    f32x4 lacc = {0.f, 0.f, 0.f, 0.f};
    #pragma unroll
    for (int j = 0; j < 4; ++j) {
        f32x4 q = eb[j];
        __builtin_nontemporal_store(q[0], &zqp[(size_t)(4 * j    ) * 4096]);
        __builtin_nontemporal_store(q[1], &zqp[(size_t)(4 * j + 1) * 4096]);
        __builtin_nontemporal_store(q[2], &zqp[(size_t)(4 * j + 2) * 4096]);
        __builtin_nontemporal_store(q[3], &zqp[(size_t)(4 * j + 3) * 4096]);
        f32x4 dq = q - zv[j];
        lacc = __builtin_elementwise_fma(dq, dq, lacc);
    }
    f32x2 lt = __builtin_shufflevector(lacc, lacc, 0, 1)
             + __builtin_shufflevector(lacc, lacc, 2, 3);
    float lsum = lt.x + lt.y;
    #pragma unroll
    for (int o = 32; o > 0; o >>= 1) lsum += __shfl_down(lsum, o);
    if ((tid & 63) == 0) atomicAdd(loss_acc, (double)lsum);

    // ---- one-hot: block cooperatively writes its 64 rows, coalesced NT ----
    // ENC_OFF % 4 == 2 elements -> only 8B-aligned; two f32x2 stores per row.
    __shared__ int sbest[64];
    if (s == 0) sbest[pl] = best;
    __syncthreads();
    const size_t blockbase = ENC_OFF + (size_t)blockIdx.x * 64 * N_E;
    const int col = tid * 4;
    for (int r = 0; r < 64; ++r) {
        const int rb = sbest[r];
        f32x2 v0 = { rb == col     ? 1.f : 0.f, rb == col + 1 ? 1.f : 0.f };
        f32x2 v1 = { rb == col + 2 ? 1.f : 0.f, rb == col + 3 ? 1.f : 0.f };
        float* dst = out + blockbase + (size_t)r * N_E + col;
        __builtin_nontemporal_store(v0, (f32x2*)dst);
        __builtin_nontemporal_store(v1, (f32x2*)(dst + 2));
    }
}

// ---- finalize: perplexity + loss ----
__global__ void vq_final(const unsigned* __restrict__ counts,
                         const double* __restrict__ loss_acc,
                         float* __restrict__ out)
{
    __shared__ float red[N_E];
    const int e = threadIdx.x;
    const float em = (float)counts[e] * (1.0f / (float)N_PIX);
    red[e] = em * logf(em + 1e-10f);
    __syncthreads();
    for (int s = 512; s > 0; s >>= 1) {
        if (e < s) red[e] += red[e + s];
        __syncthreads();
    }
    if (e == 0) {
        out[PERP_OFF] = expf(-red[0]);
        out[LOSS_OFF] = (float)((*loss_acc) * (1.25 / (double)Z_ELEMS));
    }
}

extern "C" void kernel_launch(void* const* d_in, const int* in_sizes, int n_in,
                              void* d_out, int out_size, void* d_ws, size_t ws_size,
                              hipStream_t stream) {
    const float* z   = (const float*)d_in[0];
    const float* emb = (const float*)d_in[1];
    float* out = (float*)d_out;

    unsigned* counts   = (unsigned*)d_ws;                   // 4096 B
    double*   loss_acc = (double*)((char*)d_ws + 4096);     // 8 B
    float*    ee       = (float*)((char*)d_ws + 8192);      // 4096 B

    (void)hipMemsetAsync(d_ws, 0, 4104, stream);
    vq_prep<<<4, 256, 0, stream>>>(emb, ee);
    vq_main<<<N_PIX / 64, 256, 0, stream>>>(z, emb, ee, out, counts, loss_acc);
    vq_final<<<1, N_E, 0, stream>>>(counts, loss_acc, out);
}